// Round 14
// baseline (7822.965 us; speedup 1.0000x reference)
//
#include <hip/hip_runtime.h>
#include <stdint.h>

// SingleBandLSTM: B=64, IN=16, H=512, T=1024, 2-layer LSTM, constant input per step.
// R14 = R10 structure with the flag protocol replaced by SELF-VALIDATING TAGGED DATA:
// ring words are u32 = (h_bf16 << 16) | step_tag. Producers fire tagged 4B sc1
// stores and continue (no drain, no ready flag). Consumers stage with coalesced
// dwordx4 sc1 loads + in-asm vmcnt(0), validate all tags == t, retry per-wave.
// Removes ~2 LLC RTTs (producer drain + flag RMW + poll detect) from every step.
//  - ABA across graph replays: rings memset to 0xFF each launch (tag 0xFFFF != any t)
//  - ring-recycle ABA within a run: R10's RMW done-counters as backpressure
//    (producer waits done[t-RING] before overwriting a slot; off critical path)
//  - publishes stay scattered 4B sc1 stores (R11 lesson: u64 stores write-amplify)
//  - 2 barriers/step (was 4-5)
// Kept from R10: split L0/L1 blocks, ring depth 8, fused ih+hh L1 MFMA,
// ((row&7)<<4) LDS swizzle, self-contained asm staging (R4 lesson).

#define TSEQ 1024
#define HDIM 512
#define BATCH 64
#define RING 8

typedef __attribute__((ext_vector_type(8))) short bf16x8;
typedef __attribute__((ext_vector_type(4))) float f32x4;
typedef __attribute__((ext_vector_type(4))) unsigned int u32x4;

__device__ __forceinline__ unsigned short f2bf(float f) {
  union { float f; unsigned u; } v; v.f = f;
  unsigned r = v.u + 0x7FFFu + ((v.u >> 16) & 1u);   // RNE
  return (unsigned short)(r >> 16);
}
__device__ __forceinline__ float bf2f(unsigned short s) {
  union { unsigned u; float f; } v; v.u = ((unsigned)s) << 16; return v.f;
}
__device__ __forceinline__ float sigm(float x) { return 1.0f / (1.0f + __expf(-x)); }
__device__ __forceinline__ float tanh_(float x) { return 1.0f - 2.0f / (__expf(2.0f * x) + 1.0f); }

__device__ __forceinline__ void flag_add(int* p) {
  __hip_atomic_fetch_add(p, 1, __ATOMIC_RELAXED, __HIP_MEMORY_SCOPE_AGENT);
}
__device__ __forceinline__ void flag_wait(int* p, int target) {
  while (__hip_atomic_load(p, __ATOMIC_RELAXED, __HIP_MEMORY_SCOPE_AGENT) < target)
    __builtin_amdgcn_s_sleep(1);
}
__device__ __forceinline__ void g_st32u(unsigned* p, unsigned v) {
  __hip_atomic_store(p, v, __ATOMIC_RELAXED, __HIP_MEMORY_SCOPE_AGENT);
}

// Stage one 128KB u32 ring slot [64 b][512 units u32] -> LDS bf16 [b][512u],
// XOR swizzle ((row&7)<<4). Two halves of 8 loads; per-wave validate+retry on
// the 16-bit tags; pack (hi16 pairs) -> 16B LDS quads identical to R10 layout.
__device__ __forceinline__ void stage_tag(char* lds, const unsigned* src32,
                                          int tid, int tag) {
  #pragma unroll
  for (int half = 0; half < 2; ++half) {
    u32x4 r0, r1, r2, r3, r4, r5, r6, r7;
    const char* a = (const char*)src32 + (size_t)tid * 32 + (size_t)half * 65536;
    while (true) {
      asm volatile(
          "global_load_dwordx4 %0, %8, off sc1\n\t"
          "global_load_dwordx4 %1, %9, off sc1\n\t"
          "global_load_dwordx4 %2, %10, off sc1\n\t"
          "global_load_dwordx4 %3, %11, off sc1\n\t"
          "global_load_dwordx4 %4, %12, off sc1\n\t"
          "global_load_dwordx4 %5, %13, off sc1\n\t"
          "global_load_dwordx4 %6, %14, off sc1\n\t"
          "global_load_dwordx4 %7, %15, off sc1\n\t"
          "s_waitcnt vmcnt(0)"
          : "=&v"(r0), "=&v"(r1), "=&v"(r2), "=&v"(r3),
            "=&v"(r4), "=&v"(r5), "=&v"(r6), "=&v"(r7)
          : "v"(a), "v"(a + 16), "v"(a + 16384), "v"(a + 16400),
            "v"(a + 32768), "v"(a + 32784), "v"(a + 49152), "v"(a + 49168)
          : "memory");
      bool ok = true;
      #pragma unroll
      for (int j = 0; j < 4; ++j) {
        ok &= ((r0[j] & 0xffffu) == (unsigned)tag) & ((r1[j] & 0xffffu) == (unsigned)tag);
        ok &= ((r2[j] & 0xffffu) == (unsigned)tag) & ((r3[j] & 0xffffu) == (unsigned)tag);
        ok &= ((r4[j] & 0xffffu) == (unsigned)tag) & ((r5[j] & 0xffffu) == (unsigned)tag);
        ok &= ((r6[j] & 0xffffu) == (unsigned)tag) & ((r7[j] & 0xffffu) == (unsigned)tag);
      }
      if (__all(ok)) break;
      __builtin_amdgcn_s_sleep(1);
    }
    // pack pairs -> bf16 quads and write LDS (4 quads: i = 4*half + j)
    u32x4 lo[4] = {r0, r2, r4, r6};
    u32x4 hi[4] = {r1, r3, r5, r7};
    #pragma unroll
    for (int j = 0; j < 4; ++j) {
      int q = tid + (4 * half + j) * 512;
      int row = q >> 6, kb = (q & 63) << 4;
      u32x4 outq;
      outq[0] = (lo[j][1] & 0xffff0000u) | (lo[j][0] >> 16);
      outq[1] = (lo[j][3] & 0xffff0000u) | (lo[j][2] >> 16);
      outq[2] = (hi[j][1] & 0xffff0000u) | (hi[j][0] >> 16);
      outq[3] = (hi[j][3] & 0xffff0000u) | (hi[j][2] >> 16);
      *(u32x4*)(lds + row * 1024 + (kb ^ ((row & 7) << 4))) = outq;
    }
  }
}
__device__ __forceinline__ void zero64k(char* lds, int tid) {
  u32x4 z = {0u, 0u, 0u, 0u};
  #pragma unroll
  for (int i = 0; i < 8; ++i)
    *(u32x4*)(lds + (size_t)(tid + i * 512) * 16) = z;
}

// ---------------- precompute kernels ----------------
__global__ void k_fc_in(const float* __restrict__ x, const float* __restrict__ w_in,
                        const float* __restrict__ b_in, float* __restrict__ h_in) {
  int b = blockIdx.x;      // 64
  int j = threadIdx.x;     // 512
  float acc = b_in[j];
  #pragma unroll
  for (int i = 0; i < 16; ++i) acc += x[b * 16 + i] * w_in[j * 16 + i];
  h_in[b * HDIM + j] = acc;
}

__global__ __launch_bounds__(512, 1)
void k_xg0(const float* __restrict__ h_in, const float* __restrict__ w_ih0,
           const float* __restrict__ b_ih0, const float* __restrict__ b_hh0,
           float* __restrict__ xg0) {
  __shared__ float hbuf[64 * 516];
  __shared__ float wbuf[8 * 520];
  int r0 = blockIdx.x * 8;           // 256 blocks x 8 rows = 2048 gate rows
  int tid = threadIdx.x;
  for (int i = 0; i < 64; ++i) {
    int c = tid + i * 512;
    hbuf[(c >> 9) * 516 + (c & 511)] = h_in[c];
  }
  for (int i = 0; i < 8; ++i) {
    int c = tid + i * 512;
    wbuf[(c >> 9) * 520 + (c & 511)] = w_ih0[(size_t)r0 * HDIM + c];
  }
  __syncthreads();
  int b = tid >> 3, rl = tid & 7;
  float acc = 0.f;
  for (int k = 0; k < 512; ++k) acc += hbuf[b * 516 + k] * wbuf[rl * 520 + k];
  int r = r0 + rl;
  xg0[(size_t)b * 2048 + r] = acc + b_ih0[r] + b_hh0[r];
}

// ---------------- persistent recurrence kernel ----------------
__global__ __launch_bounds__(512, 1)
void lstm_persist(const float* __restrict__ w_hh0,
                  const float* __restrict__ w_ih1,
                  const float* __restrict__ w_hh1,
                  const float* __restrict__ b_ih1,
                  const float* __restrict__ b_hh1,
                  const float* __restrict__ w_out,
                  const float* __restrict__ b_out,
                  const float* __restrict__ xg0,
                  unsigned* __restrict__ ring0,        // 8 slots x 128KB (u32 tagged)
                  unsigned* __restrict__ ring1,        // 8 slots x 128KB
                  int* __restrict__ flags,             // done counters only
                  float* __restrict__ out) {
  __shared__ __align__(16) unsigned short hA[BATCH * HDIM];  // 64KB bf16, swizzled
  __shared__ __align__(16) unsigned short hBt[BATCH * HDIM]; // 64KB bf16, swizzled
  __shared__ float gbuf[BATCH * 68];                         // gate transpose buffer
  char* hAc = (char*)hA;
  char* hBc = (char*)hBt;

  const int tid = threadIdx.x;
  const int layer = blockIdx.x & 1;
  const int p = blockIdx.x >> 1;      // 0..31 within group
  const int u0 = p * 16;              // first owned hidden unit

  const int wave = tid >> 6, lane = tid & 63;
  const int nt = wave & 3;            // N-tile (16 gate rows)
  const int mh = wave >> 2;           // M-tile pair selector
  const int ln15 = lane & 15, lg = lane >> 4;

  const int n_local = nt * 16 + ln15;
  const int grow = (n_local & 3) * HDIM + u0 + (n_local >> 2);  // global gate row

  int* h0_done = flags;               // TSEQ RMW counters (backpressure)
  int* h1_done = flags + TSEQ;

  // ---- weight fragments into registers (fp32 -> bf16) ----
  bf16x8 wh[16];  // w_hh (layer 0 or 1)
  bf16x8 wi[16];  // w_ih1 (layer 1 only)
  {
    const float* Wh = (layer == 0 ? w_hh0 : w_hh1) + (size_t)grow * HDIM;
    #pragma unroll
    for (int kt = 0; kt < 16; ++kt) {
      const float* s = Wh + kt * 32 + lg * 8;
      bf16x8 r;
      #pragma unroll
      for (int e = 0; e < 8; ++e) r[e] = (short)f2bf(s[e]);
      wh[kt] = r;
    }
  }
  if (layer == 1) {
    const float* Wi = w_ih1 + (size_t)grow * HDIM;
    #pragma unroll
    for (int kt = 0; kt < 16; ++kt) {
      const float* s = Wi + kt * 32 + lg * 8;
      bf16x8 r;
      #pragma unroll
      for (int e = 0; e < 8; ++e) r[e] = (short)f2bf(s[e]);
      wi[kt] = r;
    }
  }

  // ---- accumulator init (xg0 fragment for L0; bias for L1) ----
  f32x4 init0, init1;
  if (layer == 0) {
    #pragma unroll
    for (int r = 0; r < 4; ++r) {
      init0[r] = xg0[(size_t)(mh * 32 + lg * 4 + r) * 2048 + grow];
      init1[r] = xg0[(size_t)(mh * 32 + 16 + lg * 4 + r) * 2048 + grow];
    }
  } else {
    float bv = b_ih1[grow] + b_hh1[grow];
    #pragma unroll
    for (int r = 0; r < 4; ++r) { init0[r] = bv; init1[r] = bv; }
  }

  // cell state for this thread's two (batch,unit) pairs
  float c0 = 0.f, c1 = 0.f;
  const int pb = tid >> 3;            // batch of pair
  const int pu = (tid << 1) & 15;     // unit_local (even)

  const int r0 = mh * 32 + ln15, r1 = r0 + 16;
  const int x0 = (r0 & 7) << 4, x1 = (r1 & 7) << 4;

  const size_t SL32 = (size_t)BATCH * HDIM;   // u32 slot elems

  if (layer == 0) {
    for (int t = 0; t < TSEQ; ++t) {
      if (t > 0) stage_tag(hAc, ring0 + (size_t)((t - 1) & (RING - 1)) * SL32, tid, t - 1);
      else       zero64k(hAc, tid);
      __syncthreads();                                        // B2
      if (tid == 0 && t > 0) flag_add(&h0_done[t - 1]);

      f32x4 a0 = init0, a1 = init1;
      #pragma unroll
      for (int kt = 0; kt < 16; ++kt) {
        const int kb = kt * 64 + lg * 16;
        bf16x8 ha0 = *(const bf16x8*)(hAc + r0 * 1024 + (kb ^ x0));
        bf16x8 ha1 = *(const bf16x8*)(hAc + r1 * 1024 + (kb ^ x1));
        a0 = __builtin_amdgcn_mfma_f32_16x16x32_bf16(ha0, wh[kt], a0, 0, 0, 0);
        a1 = __builtin_amdgcn_mfma_f32_16x16x32_bf16(ha1, wh[kt], a1, 0, 0, 0);
      }
      #pragma unroll
      for (int r = 0; r < 4; ++r) {
        gbuf[(mh * 32 + lg * 4 + r) * 68 + n_local] = a0[r];
        gbuf[(mh * 32 + 16 + lg * 4 + r) * 68 + n_local] = a1[r];
      }
      if (t >= RING && tid == 0) flag_wait(&h0_done[t - RING], 64);
      __syncthreads();                                        // B1
      {
        f32x4 gA = *(const f32x4*)&gbuf[pb * 68 + pu * 4];
        f32x4 gB = *(const f32x4*)&gbuf[pb * 68 + pu * 4 + 4];
        float i0 = sigm(gA[0]), f0 = sigm(gA[1]), z0 = tanh_(gA[2]), o0 = sigm(gA[3]);
        float i1 = sigm(gB[0]), f1 = sigm(gB[1]), z1 = tanh_(gB[2]), o1 = sigm(gB[3]);
        c0 = f0 * c0 + i0 * z0;
        c1 = f1 * c1 + i1 * z1;
        unsigned w0 = ((unsigned)f2bf(o0 * tanh_(c0)) << 16) | (unsigned)t;
        unsigned w1 = ((unsigned)f2bf(o1 * tanh_(c1)) << 16) | (unsigned)t;
        unsigned* slot = ring0 + (size_t)(t & (RING - 1)) * SL32 + pb * HDIM + u0 + pu;
        g_st32u(slot, w0);
        g_st32u(slot + 1, w1);
      }
      // fire-and-forget: tags self-validate; no drain, no flag
    }
  } else {
    for (int t = 0; t < TSEQ; ++t) {
      stage_tag(hAc, ring0 + (size_t)(t & (RING - 1)) * SL32, tid, t);
      if (t > 0) stage_tag(hBc, ring1 + (size_t)((t - 1) & (RING - 1)) * SL32, tid, t - 1);
      else       zero64k(hBc, tid);
      __syncthreads();                                        // B2
      if (tid == 0) {
        flag_add(&h0_done[t]);
        if (t > 0) flag_add(&h1_done[t - 1]);
      }

      // out[:, t-1] from hB = h1[t-1] (16 threads; other waves run MFMA)
      if (t > 0 && tid < 16) {
        const int b = 2 * p + (tid >> 3), seg = tid & 7;
        const int xb = (b & 7) << 4;
        float acc = 0.f;
        #pragma unroll
        for (int i = 0; i < 8; ++i) {
          const int kb = seg * 128 + i * 16;
          bf16x8 hv = *(const bf16x8*)(hBc + b * 1024 + (kb ^ xb));
          const float* wo = w_out + (kb >> 1);
          #pragma unroll
          for (int e = 0; e < 8; ++e) acc += bf2f((unsigned short)hv[e]) * wo[e];
        }
        acc += __shfl_down(acc, 4, 8);
        acc += __shfl_down(acc, 2, 8);
        acc += __shfl_down(acc, 1, 8);
        if (seg == 0) out[b * TSEQ + (t - 1)] = acc + b_out[0];
      }

      f32x4 a0 = init0, a1 = init1;
      #pragma unroll
      for (int kt = 0; kt < 16; ++kt) {
        const int kb = kt * 64 + lg * 16;
        bf16x8 ia0 = *(const bf16x8*)(hAc + r0 * 1024 + (kb ^ x0));
        bf16x8 ia1 = *(const bf16x8*)(hAc + r1 * 1024 + (kb ^ x1));
        bf16x8 ha0 = *(const bf16x8*)(hBc + r0 * 1024 + (kb ^ x0));
        bf16x8 ha1 = *(const bf16x8*)(hBc + r1 * 1024 + (kb ^ x1));
        a0 = __builtin_amdgcn_mfma_f32_16x16x32_bf16(ia0, wi[kt], a0, 0, 0, 0);
        a1 = __builtin_amdgcn_mfma_f32_16x16x32_bf16(ia1, wi[kt], a1, 0, 0, 0);
        a0 = __builtin_amdgcn_mfma_f32_16x16x32_bf16(ha0, wh[kt], a0, 0, 0, 0);
        a1 = __builtin_amdgcn_mfma_f32_16x16x32_bf16(ha1, wh[kt], a1, 0, 0, 0);
      }
      #pragma unroll
      for (int r = 0; r < 4; ++r) {
        gbuf[(mh * 32 + lg * 4 + r) * 68 + n_local] = a0[r];
        gbuf[(mh * 32 + 16 + lg * 4 + r) * 68 + n_local] = a1[r];
      }
      if (t >= RING && tid == 0) flag_wait(&h1_done[t - RING], 32);
      __syncthreads();                                        // B1
      {
        f32x4 gA = *(const f32x4*)&gbuf[pb * 68 + pu * 4];
        f32x4 gB = *(const f32x4*)&gbuf[pb * 68 + pu * 4 + 4];
        float i0 = sigm(gA[0]), f0 = sigm(gA[1]), z0 = tanh_(gA[2]), o0 = sigm(gA[3]);
        float i1 = sigm(gB[0]), f1 = sigm(gB[1]), z1 = tanh_(gB[2]), o1 = sigm(gB[3]);
        c0 = f0 * c0 + i0 * z0;
        c1 = f1 * c1 + i1 * z1;
        unsigned w0 = ((unsigned)f2bf(o0 * tanh_(c0)) << 16) | (unsigned)t;
        unsigned w1 = ((unsigned)f2bf(o1 * tanh_(c1)) << 16) | (unsigned)t;
        unsigned* slot = ring1 + (size_t)(t & (RING - 1)) * SL32 + pb * HDIM + u0 + pu;
        g_st32u(slot, w0);
        g_st32u(slot + 1, w1);
      }
    }
    // epilogue: out[:, T-1] from h1[T-1]
    stage_tag(hBc, ring1 + (size_t)((TSEQ - 1) & (RING - 1)) * SL32, tid, TSEQ - 1);
    __syncthreads();
    if (tid < 16) {
      const int b = 2 * p + (tid >> 3), seg = tid & 7;
      const int xb = (b & 7) << 4;
      float acc = 0.f;
      #pragma unroll
      for (int i = 0; i < 8; ++i) {
        const int kb = seg * 128 + i * 16;
        bf16x8 hv = *(const bf16x8*)(hBc + b * 1024 + (kb ^ xb));
        const float* wo = w_out + (kb >> 1);
        #pragma unroll
        for (int e = 0; e < 8; ++e) acc += bf2f((unsigned short)hv[e]) * wo[e];
      }
      acc += __shfl_down(acc, 4, 8);
      acc += __shfl_down(acc, 2, 8);
      acc += __shfl_down(acc, 1, 8);
      if (seg == 0) out[b * TSEQ + (TSEQ - 1)] = acc + b_out[0];
    }
  }
}

extern "C" void kernel_launch(void* const* d_in, const int* in_sizes, int n_in,
                              void* d_out, int out_size, void* d_ws, size_t ws_size,
                              hipStream_t stream) {
  (void)in_sizes; (void)n_in; (void)out_size; (void)ws_size;
  const float* x     = (const float*)d_in[0];
  const float* w_in  = (const float*)d_in[1];
  const float* b_in  = (const float*)d_in[2];
  const float* w_ih0 = (const float*)d_in[3];
  const float* w_hh0 = (const float*)d_in[4];
  const float* b_ih0 = (const float*)d_in[5];
  const float* b_hh0 = (const float*)d_in[6];
  const float* w_ih1 = (const float*)d_in[7];
  const float* w_hh1 = (const float*)d_in[8];
  const float* b_ih1 = (const float*)d_in[9];
  const float* b_hh1 = (const float*)d_in[10];
  const float* w_out = (const float*)d_in[11];
  const float* b_out = (const float*)d_in[12];

  char* ws = (char*)d_ws;
  unsigned* ring0 = (unsigned*)(ws + 0);                        // 8 x 128KB = 1MB
  unsigned* ring1 = (unsigned*)(ws + 1048576);                  // 8 x 128KB = 1MB
  float* xg0  = (float*)(ws + 2097152);                         // 512KB
  float* h_in = (float*)(ws + 2621440);                         // 128KB
  int*   flags = (int*)(ws + 2752512);                          // 8KB

  // kill cross-replay tag ABA: 0xFFFF tag never matches t in [0,1024)
  hipMemsetAsync(ring0, 0xFF, 2097152, stream);
  hipMemsetAsync(flags, 0, 2 * TSEQ * sizeof(int), stream);
  k_fc_in<<<64, 512, 0, stream>>>(x, w_in, b_in, h_in);
  k_xg0<<<256, 512, 0, stream>>>(h_in, w_ih0, b_ih0, b_hh0, xg0);
  lstm_persist<<<64, 512, 0, stream>>>(w_hh0, w_ih1, w_hh1, b_ih1, b_hh1,
                                       w_out, b_out, xg0, ring0, ring1,
                                       flags, (float*)d_out);
}